// Round 2
// 1035.263 us; speedup vs baseline: 1.3238x; 1.3238x over previous
//
#include <hip/hip_runtime.h>
#include <hip/hip_bf16.h>
#include <stdint.h>

typedef unsigned short u16;
typedef __attribute__((ext_vector_type(8))) short bf16x8;   // 8 bf16 = 4 VGPRs
typedef __attribute__((ext_vector_type(4))) float f32x4;

#define BATCH 8
#define SEQ   1024
#define FDIM  1024
#define NHEAD 16
#define DHEAD 64

__device__ __forceinline__ float bf2f(u16 u) {
  union { unsigned int i; float f; } v; v.i = ((unsigned int)u) << 16; return v.f;
}
__device__ __forceinline__ u16 f2bf(float f) {
  union { float f; unsigned int i; } v; v.f = f;
  unsigned int x = v.i;
  return (u16)((x + 0x7fffu + ((x >> 16) & 1u)) >> 16);  // RNE
}

// load 8 contiguous elements as 8 bf16 packed in a uint4
__device__ __forceinline__ uint4 load8(const u16* p) { return *(const uint4*)p; }
__device__ __forceinline__ uint4 load8(const float* p) {
  float4 a = *(const float4*)p;
  float4 b = *(const float4*)(p + 4);
  union { u16 h[8]; uint4 v; } r;
  r.h[0] = f2bf(a.x); r.h[1] = f2bf(a.y); r.h[2] = f2bf(a.z); r.h[3] = f2bf(a.w);
  r.h[4] = f2bf(b.x); r.h[5] = f2bf(b.y); r.h[6] = f2bf(b.z); r.h[7] = f2bf(b.w);
  return r.v;
}

// ---------- 64x64 tile transpose + fp32->bf16: dst[c][r] = src[r][c] ---------
__global__ __launch_bounds__(256) void transpose_k(
    const float* __restrict__ src, u16* __restrict__ dst, int srcLd, int dstLd) {
  __shared__ u16 t[64][72];
  const int r0 = blockIdx.y * 64, c0 = blockIdx.x * 64;
  const int tid = threadIdx.x;
  for (int p = 0; p < 16; ++p) {
    int idx = p * 256 + tid, r = idx >> 6, c = idx & 63;
    t[r][c] = f2bf(src[(long)(r0 + r) * srcLd + (c0 + c)]);
  }
  __syncthreads();
  for (int p = 0; p < 16; ++p) {
    int idx = p * 256 + tid, r = idx >> 6, c = idx & 63;
    dst[(long)(c0 + r) * dstLd + (r0 + c)] = t[c][r];
  }
}

// ------------- GEMM: C = A[MxK] * Bt[NxK]^T, bf16 MFMA, fp32 acc -------------
// A may be fp32 (converted during LDS staging) or bf16 (u16).
// MODE 1: f32 out at row*ldc + col
// MODE 2: bf16 out scattered to [b,h,s,d] from row=(b,s), col=(h,d)
// MODE 3: bf16 out scattered to [b,h,d,s] from row=(b,s), col=(h,d)
// MODE 4: bf16 out at row*ldc + col  (plain [b,s,(h,d)] layout)
template<int MODE, int WGM, int WGN, int MI, int NJ, typename AT>
__global__ __launch_bounds__(256) void gemm_bt(
    const AT* __restrict__ A, const u16* __restrict__ Bt, void* __restrict__ C,
    int K, int lda, int ldb, int ldc, long aZ, long bZ) {
  constexpr int BM = WGM * MI * 16;
  constexpr int BN = WGN * NJ * 16;
  __shared__ __align__(16) u16 As[BM][40];   // 32 k + 8 pad (80B row = 16B mult)
  __shared__ __align__(16) u16 Bs[BN][40];
  const int tid = threadIdx.x;
  const int wave = tid >> 6, lane = tid & 63;
  const int quad = lane >> 4, l16 = lane & 15;
  const int wm = wave / WGN, wn = wave % WGN;
  const int m0 = blockIdx.y * BM, n0 = blockIdx.x * BN;
  const int z = blockIdx.z;
  A  += (long)z * aZ;
  Bt += (long)z * bZ;

  f32x4 acc[MI][NJ];
#pragma unroll
  for (int i = 0; i < MI; ++i)
#pragma unroll
    for (int j = 0; j < NJ; ++j) acc[i][j] = (f32x4){0.f, 0.f, 0.f, 0.f};

  const int srow = tid >> 2, scol = (tid & 3) * 8;
  for (int k0 = 0; k0 < K; k0 += 32) {
    __syncthreads();
#pragma unroll
    for (int p = 0; p < BM / 64; ++p) {
      int r = p * 64 + srow;
      *(uint4*)&As[r][scol] = load8(&A[(long)(m0 + r) * lda + k0 + scol]);
    }
#pragma unroll
    for (int p = 0; p < BN / 64; ++p) {
      int r = p * 64 + srow;
      *(uint4*)&Bs[r][scol] = load8(&Bt[(long)(n0 + r) * ldb + k0 + scol]);
    }
    __syncthreads();
    bf16x8 af[MI], bfr[NJ];
#pragma unroll
    for (int i = 0; i < MI; ++i)
      af[i] = *(const bf16x8*)&As[wm * MI * 16 + i * 16 + l16][quad * 8];
#pragma unroll
    for (int j = 0; j < NJ; ++j)
      bfr[j] = *(const bf16x8*)&Bs[wn * NJ * 16 + j * 16 + l16][quad * 8];
#pragma unroll
    for (int i = 0; i < MI; ++i)
#pragma unroll
      for (int j = 0; j < NJ; ++j)
        acc[i][j] = __builtin_amdgcn_mfma_f32_16x16x32_bf16(af[i], bfr[j], acc[i][j], 0, 0, 0);
  }

#pragma unroll
  for (int i = 0; i < MI; ++i) {
    const int rowb = m0 + wm * MI * 16 + i * 16 + quad * 4;
#pragma unroll
    for (int j = 0; j < NJ; ++j) {
      const int col = n0 + wn * NJ * 16 + j * 16 + l16;
#pragma unroll
      for (int r = 0; r < 4; ++r) {
        const float v = acc[i][j][r];
        const int row = rowb + r;
        if (MODE == 1) {
          ((float*)C)[(long)row * ldc + col] = v;
        } else if (MODE == 2) {
          int bb = row >> 10, ss = row & 1023, hh = col >> 6, dd = col & 63;
          ((u16*)C)[((long)(bb * NHEAD + hh) * SEQ + ss) * DHEAD + dd] = f2bf(v);
        } else if (MODE == 3) {
          int bb = row >> 10, ss = row & 1023, hh = col >> 6, dd = col & 63;
          ((u16*)C)[((long)(bb * NHEAD + hh) * DHEAD + dd) * SEQ + ss] = f2bf(v);
        } else {
          ((u16*)C)[(long)row * ldc + col] = f2bf(v);
        }
      }
    }
  }
}

// ---- fused attention: scores + softmax -> P (fp32, coalesced) + P@V -> Ctx --
// grid: x = q-tile (S/64), y = head, z = batch. 4 waves, each owns 16 q rows.
// Q is read from Qb [b,s,(h,d)] bf16; ctx is written back IN PLACE to the same
// region (each block reads exactly the tile it later overwrites -> race-free).
__global__ __launch_bounds__(256, 4) void attn_kernel(
    const u16* __restrict__ Qb, const u16* __restrict__ Kb,
    const u16* __restrict__ Vt, const float* __restrict__ Msk,
    float* __restrict__ P, u16* __restrict__ Ctx) {
  __shared__ __align__(16) u16 QVs[64][72];   // Q tile; reused as V tile in pass 1
  __shared__ __align__(16) u16 Ks[64][72];
  __shared__ __align__(16) float Ps[64][68];  // fp32 P tile (transpose staging)
  const int tid = threadIdx.x, wave = tid >> 6, lane = tid & 63;
  const int quad = lane >> 4, l16 = lane & 15;
  const int q0 = blockIdx.x * 64, h = blockIdx.y, b = blockIdx.z;
  const long bh = (long)b * NHEAD + h;
  const u16* Qp = Qb + ((long)b * SEQ + q0) * FDIM + h * DHEAD;
  const u16* Kp = Kb + bh * SEQ * DHEAD;
  const u16* Vp = Vt + bh * (long)DHEAD * SEQ;
  const float* Mp = Msk + ((long)b * SEQ + q0) * SEQ;
  float* Pp = P + bh * (long)SEQ * SEQ + (long)q0 * SEQ;
  u16* Cp = Ctx + ((long)b * SEQ + q0) * FDIM + h * DHEAD;

  {
    int r = tid >> 3, c = (tid & 7) * 8;
    *(uint4*)&QVs[r][c]      = *(const uint4*)&Qp[(long)r * FDIM + c];
    *(uint4*)&QVs[r + 32][c] = *(const uint4*)&Qp[(long)(r + 32) * FDIM + c];
  }
  __syncthreads();
  const bf16x8 aq0 = *(const bf16x8*)&QVs[wave * 16 + l16][quad * 8];
  const bf16x8 aq1 = *(const bf16x8*)&QVs[wave * 16 + l16][32 + quad * 8];

  float m[4], l[4], rl[4];
#pragma unroll
  for (int r = 0; r < 4; ++r) { m[r] = -3.0e38f; l[r] = 0.f; }

  // ---- pass 0: running row max + exp-sum ----
  for (int st = 0; st < SEQ / 64; ++st) {
    const int sk0 = st * 64;
    __syncthreads();
    {
      int r = tid >> 3, c = (tid & 7) * 8;
      *(uint4*)&Ks[r][c]      = *(const uint4*)&Kp[(sk0 + r) * DHEAD + c];
      *(uint4*)&Ks[r + 32][c] = *(const uint4*)&Kp[(sk0 + r + 32) * DHEAD + c];
    }
    __syncthreads();
    float sv[4][4];
#pragma unroll
    for (int j = 0; j < 4; ++j) {
      bf16x8 bk0 = *(const bf16x8*)&Ks[j * 16 + l16][quad * 8];
      bf16x8 bk1 = *(const bf16x8*)&Ks[j * 16 + l16][32 + quad * 8];
      f32x4 sc = (f32x4){0.f, 0.f, 0.f, 0.f};
      sc = __builtin_amdgcn_mfma_f32_16x16x32_bf16(aq0, bk0, sc, 0, 0, 0);
      sc = __builtin_amdgcn_mfma_f32_16x16x32_bf16(aq1, bk1, sc, 0, 0, 0);
#pragma unroll
      for (int r = 0; r < 4; ++r) {
        int qr = wave * 16 + quad * 4 + r;
        float mk = Mp[(long)qr * SEQ + sk0 + j * 16 + l16];
        sv[j][r] = sc[r] * 0.125f + (mk - 1.0f) * 1.0e9f;
      }
    }
#pragma unroll
    for (int r = 0; r < 4; ++r) {
      float tm = fmaxf(fmaxf(sv[0][r], sv[1][r]), fmaxf(sv[2][r], sv[3][r]));
#pragma unroll
      for (int off = 1; off < 16; off <<= 1) tm = fmaxf(tm, __shfl_xor(tm, off, 64));
      float mn = fmaxf(m[r], tm);
      float ps = __expf(sv[0][r] - mn) + __expf(sv[1][r] - mn) +
                 __expf(sv[2][r] - mn) + __expf(sv[3][r] - mn);
#pragma unroll
      for (int off = 1; off < 16; off <<= 1) ps += __shfl_xor(ps, off, 64);
      l[r] = l[r] * __expf(m[r] - mn) + ps;
      m[r] = mn;
    }
  }
#pragma unroll
  for (int r = 0; r < 4; ++r) rl[r] = 1.0f / l[r];

  // ---- pass 1: normalized P tile -> LDS -> {global (coalesced), PV MFMA} ----
  f32x4 acc[4];
#pragma unroll
  for (int n = 0; n < 4; ++n) acc[n] = (f32x4){0.f, 0.f, 0.f, 0.f};

  for (int st = 0; st < SEQ / 64; ++st) {
    const int sk0 = st * 64;
    __syncthreads();
    {
      int r = tid >> 3, c = (tid & 7) * 8;
      *(uint4*)&Ks[r][c]       = *(const uint4*)&Kp[(sk0 + r) * DHEAD + c];
      *(uint4*)&Ks[r + 32][c]  = *(const uint4*)&Kp[(sk0 + r + 32) * DHEAD + c];
      *(uint4*)&QVs[r][c]      = *(const uint4*)&Vp[(long)r * SEQ + sk0 + c];
      *(uint4*)&QVs[r + 32][c] = *(const uint4*)&Vp[(long)(r + 32) * SEQ + sk0 + c];
    }
    __syncthreads();
#pragma unroll
    for (int j = 0; j < 4; ++j) {
      bf16x8 bk0 = *(const bf16x8*)&Ks[j * 16 + l16][quad * 8];
      bf16x8 bk1 = *(const bf16x8*)&Ks[j * 16 + l16][32 + quad * 8];
      f32x4 sc = (f32x4){0.f, 0.f, 0.f, 0.f};
      sc = __builtin_amdgcn_mfma_f32_16x16x32_bf16(aq0, bk0, sc, 0, 0, 0);
      sc = __builtin_amdgcn_mfma_f32_16x16x32_bf16(aq1, bk1, sc, 0, 0, 0);
#pragma unroll
      for (int r = 0; r < 4; ++r) {
        int qr = wave * 16 + quad * 4 + r;
        float mk = Mp[(long)qr * SEQ + sk0 + j * 16 + l16];
        float s = sc[r] * 0.125f + (mk - 1.0f) * 1.0e9f;
        Ps[qr][j * 16 + l16] = __expf(s - m[r]) * rl[r];
      }
    }
    __syncthreads();  // Ps transpose handoff (cross-lane)
    // PV: acc[n] += P_tile(wave's 16 rows) x V_tile
#pragma unroll
    for (int ks = 0; ks < 2; ++ks) {
      const float* pr = &Ps[wave * 16 + l16][ks * 32 + quad * 8];
      f32x4 plo = *(const f32x4*)pr;
      f32x4 phi = *(const f32x4*)(pr + 4);
      union { u16 h[8]; bf16x8 v; } pa;
      pa.h[0] = f2bf(plo.x); pa.h[1] = f2bf(plo.y);
      pa.h[2] = f2bf(plo.z); pa.h[3] = f2bf(plo.w);
      pa.h[4] = f2bf(phi.x); pa.h[5] = f2bf(phi.y);
      pa.h[6] = f2bf(phi.z); pa.h[7] = f2bf(phi.w);
#pragma unroll
      for (int n = 0; n < 4; ++n) {
        bf16x8 bv = *(const bf16x8*)&QVs[n * 16 + l16][ks * 32 + quad * 8];
        acc[n] = __builtin_amdgcn_mfma_f32_16x16x32_bf16(pa.v, bv, acc[n], 0, 0, 0);
      }
    }
    // coalesced nontemporal global P write: 4 rows x 256B per instruction
#pragma unroll
    for (int rr = 0; rr < 4; ++rr) {
      const int row = wave * 16 + rr * 4 + quad;
      f32x4 val = *(const f32x4*)&Ps[row][l16 * 4];
      __builtin_nontemporal_store(val, (f32x4*)&Pp[(long)row * SEQ + sk0 + l16 * 4]);
    }
  }

  // ---- ctx epilogue -> Ctx bf16 [b,s,(h,d)] (in-place over Q tile) ----
#pragma unroll
  for (int n = 0; n < 4; ++n)
#pragma unroll
    for (int r = 0; r < 4; ++r)
      Cp[(long)(wave * 16 + quad * 4 + r) * FDIM + n * 16 + l16] = f2bf(acc[n][r]);
}

// --------------- residual + LayerNorm (weight=1, bias=0) ---------------------
__global__ __launch_bounds__(256) void ln_kernel(
    const float* __restrict__ O, const float* __restrict__ Xq, float* __restrict__ out) {
  const int row = blockIdx.x, tid = threadIdx.x;
  const float4 o = *(const float4*)&O[(long)row * FDIM + tid * 4];
  const float4 q = *(const float4*)&Xq[(long)row * FDIM + tid * 4];
  float x[4] = { o.x + q.x, o.y + q.y, o.z + q.z, o.w + q.w };
  float s  = x[0] + x[1] + x[2] + x[3];
  float s2 = x[0]*x[0] + x[1]*x[1] + x[2]*x[2] + x[3]*x[3];
#pragma unroll
  for (int off = 32; off; off >>= 1) {
    s  += __shfl_xor(s, off, 64);
    s2 += __shfl_xor(s2, off, 64);
  }
  __shared__ float red[8];
  const int wave = tid >> 6, lane = tid & 63;
  if (lane == 0) { red[wave] = s; red[4 + wave] = s2; }
  __syncthreads();
  s  = red[0] + red[1] + red[2] + red[3];
  s2 = red[4] + red[5] + red[6] + red[7];
  const float mu = s * (1.0f / FDIM);
  const float var = s2 * (1.0f / FDIM) - mu * mu;
  const float rs = rsqrtf(var + 1e-5f);
  float4 res;
  res.x = (x[0] - mu) * rs; res.y = (x[1] - mu) * rs;
  res.z = (x[2] - mu) * rs; res.w = (x[3] - mu) * rs;
  *(float4*)&out[(long)row * FDIM + tid * 4] = res;
}

extern "C" void kernel_launch(void* const* d_in, const int* in_sizes, int n_in,
                              void* d_out, int out_size, void* d_ws, size_t ws_size,
                              hipStream_t stream) {
  const float* Xq = (const float*)d_in[0];
  const float* Xk = (const float*)d_in[1];
  const float* Xv = (const float*)d_in[2];
  const float* Mk = (const float*)d_in[3];
  const float* Wq = (const float*)d_in[4];
  const float* Wk = (const float*)d_in[5];
  const float* Wv = (const float*)d_in[6];
  const float* Wo = (const float*)d_in[7];

  // ws layout (u16 units), total 56 MB:
  //  [0,1M)=WtQ [1M,2M)=WtK [2M,3M)=WtV [3M,4M)=WtO
  //  [4M,12M)=Qb [b,s,(h,d)] bf16 -> overwritten in place with Ctx by attn
  //  [12M,20M)=Kb [b,h,s,d]   [20M,28M)=Vt [b,h,d,s]
  //  alias: O(f32,32MB) <- Kb+Vt region after attn (both dead)
  u16* ws  = (u16*)d_ws;
  const size_t M = 1u << 20;
  u16* WtQ = ws;
  u16* WtK = ws + 1 * M;
  u16* WtV = ws + 2 * M;
  u16* WtO = ws + 3 * M;
  u16* Qb  = ws + 4 * M;             // [b,s,(h,d)] bf16; becomes Ctx
  u16* Kb  = ws + 12 * M;            // [b,h,s,d] bf16
  u16* Vt  = ws + 20 * M;            // [b,h,d,s] bf16
  float* O = (float*)(ws + 12 * M);  // fp32 (Kb,Vt dead after attn)

  float* out = (float*)d_out;                            // [b,s,f] fp32
  float* P   = out + (size_t)BATCH * SEQ * FDIM;         // attn probs fp32

  // weight transposes + bf16 convert: Wt[n][k] = W[k][n]
  transpose_k<<<dim3(16, 16, 1), 256, 0, stream>>>(Wq, WtQ, FDIM, FDIM);
  transpose_k<<<dim3(16, 16, 1), 256, 0, stream>>>(Wk, WtK, FDIM, FDIM);
  transpose_k<<<dim3(16, 16, 1), 256, 0, stream>>>(Wv, WtV, FDIM, FDIM);
  transpose_k<<<dim3(16, 16, 1), 256, 0, stream>>>(Wo, WtO, FDIM, FDIM);
  // projections (A fp32 converted in staging)
  gemm_bt<4, 2, 2, 4, 4><<<dim3(8, 64, 1), 256, 0, stream>>>(Xq, WtQ, Qb, FDIM, FDIM, FDIM, FDIM, 0, 0);
  gemm_bt<2, 2, 2, 4, 4><<<dim3(8, 64, 1), 256, 0, stream>>>(Xk, WtK, Kb, FDIM, FDIM, FDIM, 0, 0, 0);
  gemm_bt<3, 2, 2, 4, 4><<<dim3(8, 64, 1), 256, 0, stream>>>(Xv, WtV, Vt, FDIM, FDIM, FDIM, 0, 0, 0);
  // fused scores + softmax -> P, and P@V -> Ctx (in place over Qb)
  attn_kernel<<<dim3(SEQ / 64, NHEAD, BATCH), 256, 0, stream>>>(Qb, Kb, Vt, Mk, P, Qb);
  // out projection -> O (fp32)
  gemm_bt<1, 2, 2, 4, 4><<<dim3(8, 64, 1), 256, 0, stream>>>(Qb, WtO, O, FDIM, FDIM, FDIM, FDIM, 0, 0);
  // residual + LayerNorm -> out (fp32)
  ln_kernel<<<dim3(BATCH * SEQ, 1, 1), 256, 0, stream>>>(O, Xq, out);
}

// Round 3
// 1003.722 us; speedup vs baseline: 1.3654x; 1.0314x over previous
//
#include <hip/hip_runtime.h>
#include <hip/hip_bf16.h>
#include <stdint.h>

typedef unsigned short u16;
typedef unsigned int u32;
typedef __attribute__((ext_vector_type(8))) short bf16x8;   // 8 bf16 = 4 VGPRs
typedef __attribute__((ext_vector_type(4))) float f32x4;

#define BATCH 8
#define SEQ   1024
#define FDIM  1024
#define NHEAD 16
#define DHEAD 64

__device__ __forceinline__ float bf2f(u16 u) {
  union { unsigned int i; float f; } v; v.i = ((unsigned int)u) << 16; return v.f;
}
__device__ __forceinline__ u16 f2bf(float f) {
  union { float f; unsigned int i; } v; v.f = f;
  unsigned int x = v.i;
  return (u16)((x + 0x7fffu + ((x >> 16) & 1u)) >> 16);  // RNE
}

// load 8 contiguous elements as 8 bf16 packed in a uint4
__device__ __forceinline__ uint4 load8(const u16* p) { return *(const uint4*)p; }
__device__ __forceinline__ uint4 load8(const float* p) {
  float4 a = *(const float4*)p;
  float4 b = *(const float4*)(p + 4);
  union { u16 h[8]; uint4 v; } r;
  r.h[0] = f2bf(a.x); r.h[1] = f2bf(a.y); r.h[2] = f2bf(a.z); r.h[3] = f2bf(a.w);
  r.h[4] = f2bf(b.x); r.h[5] = f2bf(b.y); r.h[6] = f2bf(b.z); r.h[7] = f2bf(b.w);
  return r.v;
}

// async global->LDS, 16B per lane; LDS dest is wave-uniform base + lane*16
__device__ __forceinline__ void gload16(const u16* g, u16* l) {
  __builtin_amdgcn_global_load_lds(
      (__attribute__((address_space(1))) u32*)(u16*)g,
      (__attribute__((address_space(3))) u32*)l, 16, 0, 0);
}

// ---------------- fp32 -> bf16 bulk convert (8 elems/thread) -----------------
__global__ __launch_bounds__(256) void cvt_k(
    const float* __restrict__ in, u16* __restrict__ out) {
  const long i = ((long)blockIdx.x * 256 + threadIdx.x) * 8;
  *(uint4*)&out[i] = load8(&in[i]);
}

// ---------- 64x64 tile transpose + fp32->bf16: dst[c][r] = src[r][c] ---------
__global__ __launch_bounds__(256) void transpose_k(
    const float* __restrict__ src, u16* __restrict__ dst, int srcLd, int dstLd) {
  __shared__ u16 t[64][72];
  const int r0 = blockIdx.y * 64, c0 = blockIdx.x * 64;
  const int tid = threadIdx.x;
  for (int p = 0; p < 16; ++p) {
    int idx = p * 256 + tid, r = idx >> 6, c = idx & 63;
    t[r][c] = f2bf(src[(long)(r0 + r) * srcLd + (c0 + c)]);
  }
  __syncthreads();
  for (int p = 0; p < 16; ++p) {
    int idx = p * 256 + tid, r = idx >> 6, c = idx & 63;
    dst[(long)(c0 + r) * dstLd + (r0 + c)] = t[c][r];
  }
}

// -------- GEMM (all-bf16): C = A[MxK] * Bt[NxK]^T, m97-style staging --------
// 128x128 tile, BK=32, 4 waves (2x2), global_load_lds width-16, linear LDS.
// grid must be dim3(8, M/128): N=1024 fixed. XCD-bijective swizzle (nwg%8==0).
// MODE 1: f32 out at row*ldc + col
// MODE 2: bf16 out scattered to [b,h,s,d] from row=(b,s), col=(h,d)
// MODE 3: bf16 out scattered to [b,h,d,s] from row=(b,s), col=(h,d)
// MODE 4: bf16 out at row*ldc + col
template<int MODE>
__global__ __launch_bounds__(256) void gemm16(
    const u16* __restrict__ A, const u16* __restrict__ Bt, void* __restrict__ C,
    int K, int lda, int ldb, int ldc) {
  __shared__ __align__(16) u16 As[128 * 32];   // linear [row][32]
  __shared__ __align__(16) u16 Bs[128 * 32];
  const int tid = threadIdx.x;
  const int wave = tid >> 6, lane = tid & 63;
  const int quad = lane >> 4, l16 = lane & 15;
  const int wm = wave >> 1, wn = wave & 1;
  // XCD swizzle: XCD x gets a contiguous chunk of 64 tiles (8 A-panels reused)
  const int bid = blockIdx.y * 8 + blockIdx.x;
  const int cpx = (gridDim.y * 8) >> 3;
  const int swz = (bid & 7) * cpx + (bid >> 3);
  const int m0 = (swz >> 3) * 128, n0 = (swz & 7) * 128;

  f32x4 acc[4][4];
#pragma unroll
  for (int i = 0; i < 4; ++i)
#pragma unroll
    for (int j = 0; j < 4; ++j) acc[i][j] = (f32x4){0.f, 0.f, 0.f, 0.f};

  // staging: wave w owns rows [32w, 32w+32). lane l -> row l>>2, 16B seg l&3.
  const int srow = lane >> 2, scol = (lane & 3) * 8;
  const u16* ga = &A[(long)(m0 + wave * 32 + srow) * lda + scol];
  const u16* gb = &Bt[(long)(n0 + wave * 32 + srow) * ldb + scol];
  u16* la0 = &As[(wave * 32) * 32];
  u16* la1 = &As[(wave * 32 + 16) * 32];
  u16* lb0 = &Bs[(wave * 32) * 32];
  u16* lb1 = &Bs[(wave * 32 + 16) * 32];

  for (int k0 = 0; k0 < K; k0 += 32) {
    __syncthreads();
    gload16(ga + k0,            la0);
    gload16(ga + k0 + 16 * lda, la1);
    gload16(gb + k0,            lb0);
    gload16(gb + k0 + 16 * ldb, lb1);
    __syncthreads();   // drains vmcnt (compiler inserts waitcnt before barrier)
    bf16x8 af[4], bfr[4];
#pragma unroll
    for (int i = 0; i < 4; ++i)
      af[i] = *(const bf16x8*)&As[(wm * 64 + i * 16 + l16) * 32 + quad * 8];
#pragma unroll
    for (int j = 0; j < 4; ++j)
      bfr[j] = *(const bf16x8*)&Bs[(wn * 64 + j * 16 + l16) * 32 + quad * 8];
#pragma unroll
    for (int i = 0; i < 4; ++i)
#pragma unroll
      for (int j = 0; j < 4; ++j)
        acc[i][j] = __builtin_amdgcn_mfma_f32_16x16x32_bf16(af[i], bfr[j], acc[i][j], 0, 0, 0);
  }

#pragma unroll
  for (int i = 0; i < 4; ++i) {
    const int rowb = m0 + wm * 64 + i * 16 + quad * 4;
#pragma unroll
    for (int j = 0; j < 4; ++j) {
      const int col = n0 + wn * 64 + j * 16 + l16;
#pragma unroll
      for (int r = 0; r < 4; ++r) {
        const float v = acc[i][j][r];
        const int row = rowb + r;
        if (MODE == 1) {
          ((float*)C)[(long)row * ldc + col] = v;
        } else if (MODE == 2) {
          int bb = row >> 10, ss = row & 1023, hh = col >> 6, dd = col & 63;
          ((u16*)C)[((long)(bb * NHEAD + hh) * SEQ + ss) * DHEAD + dd] = f2bf(v);
        } else if (MODE == 3) {
          int bb = row >> 10, ss = row & 1023, hh = col >> 6, dd = col & 63;
          ((u16*)C)[((long)(bb * NHEAD + hh) * DHEAD + dd) * SEQ + ss] = f2bf(v);
        } else {
          ((u16*)C)[(long)row * ldc + col] = f2bf(v);
        }
      }
    }
  }
}

// ---- fused attention: scores + softmax -> P (fp32, coalesced) + P@V -> Ctx --
// grid: x = q-tile (S/64), y = head, z = batch. 4 waves, each owns 16 q rows.
// Q is read from Qb [b,s,(h,d)] bf16; ctx is written back IN PLACE to the same
// region (each block reads exactly the tile it later overwrites -> race-free).
__global__ __launch_bounds__(256, 4) void attn_kernel(
    const u16* __restrict__ Qb, const u16* __restrict__ Kb,
    const u16* __restrict__ Vt, const float* __restrict__ Msk,
    float* __restrict__ P, u16* __restrict__ Ctx) {
  __shared__ __align__(16) u16 QVs[64][72];   // Q tile; reused as V tile in pass 1
  __shared__ __align__(16) u16 Ks[64][72];
  __shared__ __align__(16) float Ps[64][68];  // fp32 P tile (transpose staging)
  const int tid = threadIdx.x, wave = tid >> 6, lane = tid & 63;
  const int quad = lane >> 4, l16 = lane & 15;
  const int q0 = blockIdx.x * 64, h = blockIdx.y, b = blockIdx.z;
  const long bh = (long)b * NHEAD + h;
  const u16* Qp = Qb + ((long)b * SEQ + q0) * FDIM + h * DHEAD;
  const u16* Kp = Kb + bh * SEQ * DHEAD;
  const u16* Vp = Vt + bh * (long)DHEAD * SEQ;
  const float* Mp = Msk + ((long)b * SEQ + q0) * SEQ;
  float* Pp = P + bh * (long)SEQ * SEQ + (long)q0 * SEQ;
  u16* Cp = Ctx + ((long)b * SEQ + q0) * FDIM + h * DHEAD;

  {
    int r = tid >> 3, c = (tid & 7) * 8;
    *(uint4*)&QVs[r][c]      = *(const uint4*)&Qp[(long)r * FDIM + c];
    *(uint4*)&QVs[r + 32][c] = *(const uint4*)&Qp[(long)(r + 32) * FDIM + c];
  }
  __syncthreads();
  const bf16x8 aq0 = *(const bf16x8*)&QVs[wave * 16 + l16][quad * 8];
  const bf16x8 aq1 = *(const bf16x8*)&QVs[wave * 16 + l16][32 + quad * 8];

  float m[4], l[4], rl[4];
#pragma unroll
  for (int r = 0; r < 4; ++r) { m[r] = -3.0e38f; l[r] = 0.f; }

  // ---- pass 0: running row max + exp-sum ----
  for (int st = 0; st < SEQ / 64; ++st) {
    const int sk0 = st * 64;
    __syncthreads();
    {
      int r = tid >> 3, c = (tid & 7) * 8;
      *(uint4*)&Ks[r][c]      = *(const uint4*)&Kp[(sk0 + r) * DHEAD + c];
      *(uint4*)&Ks[r + 32][c] = *(const uint4*)&Kp[(sk0 + r + 32) * DHEAD + c];
    }
    __syncthreads();
    float sv[4][4];
#pragma unroll
    for (int j = 0; j < 4; ++j) {
      bf16x8 bk0 = *(const bf16x8*)&Ks[j * 16 + l16][quad * 8];
      bf16x8 bk1 = *(const bf16x8*)&Ks[j * 16 + l16][32 + quad * 8];
      f32x4 sc = (f32x4){0.f, 0.f, 0.f, 0.f};
      sc = __builtin_amdgcn_mfma_f32_16x16x32_bf16(aq0, bk0, sc, 0, 0, 0);
      sc = __builtin_amdgcn_mfma_f32_16x16x32_bf16(aq1, bk1, sc, 0, 0, 0);
#pragma unroll
      for (int r = 0; r < 4; ++r) {
        int qr = wave * 16 + quad * 4 + r;
        float mk = Mp[(long)qr * SEQ + sk0 + j * 16 + l16];
        sv[j][r] = sc[r] * 0.125f + (mk - 1.0f) * 1.0e9f;
      }
    }
#pragma unroll
    for (int r = 0; r < 4; ++r) {
      float tm = fmaxf(fmaxf(sv[0][r], sv[1][r]), fmaxf(sv[2][r], sv[3][r]));
#pragma unroll
      for (int off = 1; off < 16; off <<= 1) tm = fmaxf(tm, __shfl_xor(tm, off, 64));
      float mn = fmaxf(m[r], tm);
      float ps = __expf(sv[0][r] - mn) + __expf(sv[1][r] - mn) +
                 __expf(sv[2][r] - mn) + __expf(sv[3][r] - mn);
#pragma unroll
      for (int off = 1; off < 16; off <<= 1) ps += __shfl_xor(ps, off, 64);
      l[r] = l[r] * __expf(m[r] - mn) + ps;
      m[r] = mn;
    }
  }
#pragma unroll
  for (int r = 0; r < 4; ++r) rl[r] = 1.0f / l[r];

  // ---- pass 1: normalized P tile -> LDS -> {global (coalesced), PV MFMA} ----
  f32x4 acc[4];
#pragma unroll
  for (int n = 0; n < 4; ++n) acc[n] = (f32x4){0.f, 0.f, 0.f, 0.f};

  for (int st = 0; st < SEQ / 64; ++st) {
    const int sk0 = st * 64;
    __syncthreads();
    {
      int r = tid >> 3, c = (tid & 7) * 8;
      *(uint4*)&Ks[r][c]       = *(const uint4*)&Kp[(sk0 + r) * DHEAD + c];
      *(uint4*)&Ks[r + 32][c]  = *(const uint4*)&Kp[(sk0 + r + 32) * DHEAD + c];
      *(uint4*)&QVs[r][c]      = *(const uint4*)&Vp[(long)r * SEQ + sk0 + c];
      *(uint4*)&QVs[r + 32][c] = *(const uint4*)&Vp[(long)(r + 32) * SEQ + sk0 + c];
    }
    __syncthreads();
#pragma unroll
    for (int j = 0; j < 4; ++j) {
      bf16x8 bk0 = *(const bf16x8*)&Ks[j * 16 + l16][quad * 8];
      bf16x8 bk1 = *(const bf16x8*)&Ks[j * 16 + l16][32 + quad * 8];
      f32x4 sc = (f32x4){0.f, 0.f, 0.f, 0.f};
      sc = __builtin_amdgcn_mfma_f32_16x16x32_bf16(aq0, bk0, sc, 0, 0, 0);
      sc = __builtin_amdgcn_mfma_f32_16x16x32_bf16(aq1, bk1, sc, 0, 0, 0);
#pragma unroll
      for (int r = 0; r < 4; ++r) {
        int qr = wave * 16 + quad * 4 + r;
        float mk = Mp[(long)qr * SEQ + sk0 + j * 16 + l16];
        float s = sc[r] * 0.125f + (mk - 1.0f) * 1.0e9f;
        Ps[qr][j * 16 + l16] = __expf(s - m[r]) * rl[r];
      }
    }
    __syncthreads();  // Ps transpose handoff (cross-lane)
    // PV: acc[n] += P_tile(wave's 16 rows) x V_tile
#pragma unroll
    for (int ks = 0; ks < 2; ++ks) {
      const float* pr = &Ps[wave * 16 + l16][ks * 32 + quad * 8];
      f32x4 plo = *(const f32x4*)pr;
      f32x4 phi = *(const f32x4*)(pr + 4);
      union { u16 h[8]; bf16x8 v; } pa;
      pa.h[0] = f2bf(plo.x); pa.h[1] = f2bf(plo.y);
      pa.h[2] = f2bf(plo.z); pa.h[3] = f2bf(plo.w);
      pa.h[4] = f2bf(phi.x); pa.h[5] = f2bf(phi.y);
      pa.h[6] = f2bf(phi.z); pa.h[7] = f2bf(phi.w);
#pragma unroll
      for (int n = 0; n < 4; ++n) {
        bf16x8 bv = *(const bf16x8*)&QVs[n * 16 + l16][ks * 32 + quad * 8];
        acc[n] = __builtin_amdgcn_mfma_f32_16x16x32_bf16(pa.v, bv, acc[n], 0, 0, 0);
      }
    }
    // coalesced nontemporal global P write: 4 rows x 256B per instruction
#pragma unroll
    for (int rr = 0; rr < 4; ++rr) {
      const int row = wave * 16 + rr * 4 + quad;
      f32x4 val = *(const f32x4*)&Ps[row][l16 * 4];
      __builtin_nontemporal_store(val, (f32x4*)&Pp[(long)row * SEQ + sk0 + l16 * 4]);
    }
  }

  // ---- ctx epilogue -> Ctx bf16 [b,s,(h,d)] (in-place over Q tile) ----
#pragma unroll
  for (int n = 0; n < 4; ++n)
#pragma unroll
    for (int r = 0; r < 4; ++r)
      Cp[(long)(wave * 16 + quad * 4 + r) * FDIM + n * 16 + l16] = f2bf(acc[n][r]);
}

// --------------- residual + LayerNorm (weight=1, bias=0) ---------------------
__global__ __launch_bounds__(256) void ln_kernel(
    const float* __restrict__ O, const float* __restrict__ Xq, float* __restrict__ out) {
  const int row = blockIdx.x, tid = threadIdx.x;
  const float4 o = *(const float4*)&O[(long)row * FDIM + tid * 4];
  const float4 q = *(const float4*)&Xq[(long)row * FDIM + tid * 4];
  float x[4] = { o.x + q.x, o.y + q.y, o.z + q.z, o.w + q.w };
  float s  = x[0] + x[1] + x[2] + x[3];
  float s2 = x[0]*x[0] + x[1]*x[1] + x[2]*x[2] + x[3]*x[3];
#pragma unroll
  for (int off = 32; off; off >>= 1) {
    s  += __shfl_xor(s, off, 64);
    s2 += __shfl_xor(s2, off, 64);
  }
  __shared__ float red[8];
  const int wave = tid >> 6, lane = tid & 63;
  if (lane == 0) { red[wave] = s; red[4 + wave] = s2; }
  __syncthreads();
  s  = red[0] + red[1] + red[2] + red[3];
  s2 = red[4] + red[5] + red[6] + red[7];
  const float mu = s * (1.0f / FDIM);
  const float var = s2 * (1.0f / FDIM) - mu * mu;
  const float rs = rsqrtf(var + 1e-5f);
  float4 res;
  res.x = (x[0] - mu) * rs; res.y = (x[1] - mu) * rs;
  res.z = (x[2] - mu) * rs; res.w = (x[3] - mu) * rs;
  *(float4*)&out[(long)row * FDIM + tid * 4] = res;
}

extern "C" void kernel_launch(void* const* d_in, const int* in_sizes, int n_in,
                              void* d_out, int out_size, void* d_ws, size_t ws_size,
                              hipStream_t stream) {
  const float* Xq = (const float*)d_in[0];
  const float* Xk = (const float*)d_in[1];
  const float* Xv = (const float*)d_in[2];
  const float* Mk = (const float*)d_in[3];
  const float* Wq = (const float*)d_in[4];
  const float* Wk = (const float*)d_in[5];
  const float* Wv = (const float*)d_in[6];
  const float* Wo = (const float*)d_in[7];

  // ws layout (u16 units), total 56 MB:
  //  [0,1M)=WtQ [1M,2M)=WtK [2M,3M)=WtV [3M,4M)=WtO
  //  [4M,12M)=Qb [b,s,(h,d)] bf16 -> overwritten in place with Ctx by attn
  //  [12M,20M)=Kb [b,h,s,d]   [20M,28M)=Vt [b,h,d,s]
  //  alias: O(f32,32MB) <- Kb+Vt region after attn (both dead)
  u16* ws  = (u16*)d_ws;
  const size_t M = 1u << 20;
  u16* WtQ = ws;
  u16* WtK = ws + 1 * M;
  u16* WtV = ws + 2 * M;
  u16* WtO = ws + 3 * M;
  u16* Qb  = ws + 4 * M;             // [b,s,(h,d)] bf16; becomes Ctx
  u16* Kb  = ws + 12 * M;            // [b,h,s,d] bf16
  u16* Vt  = ws + 20 * M;            // [b,h,d,s] bf16
  float* O = (float*)(ws + 12 * M);  // fp32 (Kb,Vt dead after attn)

  float* out = (float*)d_out;                            // [b,s,f] fp32
  float* P   = out + (size_t)BATCH * SEQ * FDIM;         // attn probs fp32

  // bf16 input copies live in the (currently dead) P region of d_out:
  // attn overwrites them only after the projections have consumed them.
  u16* Xqb = (u16*)P;
  u16* Xkb = (u16*)P + 8 * M;
  u16* Xvb = (u16*)P + 16 * M;

  // fp32 -> bf16 bulk converts (8M elems each)
  cvt_k<<<dim3(4096, 1, 1), 256, 0, stream>>>(Xq, Xqb);
  cvt_k<<<dim3(4096, 1, 1), 256, 0, stream>>>(Xk, Xkb);
  cvt_k<<<dim3(4096, 1, 1), 256, 0, stream>>>(Xv, Xvb);
  // weight transposes + bf16 convert: Wt[n][k] = W[k][n]
  transpose_k<<<dim3(16, 16, 1), 256, 0, stream>>>(Wq, WtQ, FDIM, FDIM);
  transpose_k<<<dim3(16, 16, 1), 256, 0, stream>>>(Wk, WtK, FDIM, FDIM);
  transpose_k<<<dim3(16, 16, 1), 256, 0, stream>>>(Wv, WtV, FDIM, FDIM);
  transpose_k<<<dim3(16, 16, 1), 256, 0, stream>>>(Wo, WtO, FDIM, FDIM);
  // projections (all-bf16, global_load_lds staging)
  gemm16<4><<<dim3(8, 64, 1), 256, 0, stream>>>(Xqb, WtQ, Qb, FDIM, FDIM, FDIM, FDIM);
  gemm16<2><<<dim3(8, 64, 1), 256, 0, stream>>>(Xkb, WtK, Kb, FDIM, FDIM, FDIM, 0);
  gemm16<3><<<dim3(8, 64, 1), 256, 0, stream>>>(Xvb, WtV, Vt, FDIM, FDIM, FDIM, 0);
  // fused scores + softmax -> P, and P@V -> Ctx (in place over Qb)
  attn_kernel<<<dim3(SEQ / 64, NHEAD, BATCH), 256, 0, stream>>>(Qb, Kb, Vt, Mk, P, Qb);
  // out projection -> O (fp32)
  gemm16<1><<<dim3(8, 64, 1), 256, 0, stream>>>(Qb, WtO, O, FDIM, FDIM, FDIM, FDIM);
  // residual + LayerNorm -> out (fp32)
  ln_kernel<<<dim3(BATCH * SEQ, 1, 1), 256, 0, stream>>>(O, Xq, out);
}

// Round 4
// 926.679 us; speedup vs baseline: 1.4789x; 1.0831x over previous
//
#include <hip/hip_runtime.h>
#include <hip/hip_bf16.h>
#include <stdint.h>

typedef unsigned short u16;
typedef unsigned int u32;
typedef __attribute__((ext_vector_type(8))) short bf16x8;   // 8 bf16 = 4 VGPRs
typedef __attribute__((ext_vector_type(4))) float f32x4;

#define BATCH 8
#define SEQ   1024
#define FDIM  1024
#define NHEAD 16
#define DHEAD 64

__device__ __forceinline__ float bf2f(u16 u) {
  union { unsigned int i; float f; } v; v.i = ((unsigned int)u) << 16; return v.f;
}
__device__ __forceinline__ u16 f2bf(float f) {
  union { float f; unsigned int i; } v; v.f = f;
  unsigned int x = v.i;
  return (u16)((x + 0x7fffu + ((x >> 16) & 1u)) >> 16);  // RNE
}

// load 8 contiguous elements as 8 bf16 packed in a uint4
__device__ __forceinline__ uint4 load8(const u16* p) { return *(const uint4*)p; }
__device__ __forceinline__ uint4 load8(const float* p) {
  float4 a = *(const float4*)p;
  float4 b = *(const float4*)(p + 4);
  union { u16 h[8]; uint4 v; } r;
  r.h[0] = f2bf(a.x); r.h[1] = f2bf(a.y); r.h[2] = f2bf(a.z); r.h[3] = f2bf(a.w);
  r.h[4] = f2bf(b.x); r.h[5] = f2bf(b.y); r.h[6] = f2bf(b.z); r.h[7] = f2bf(b.w);
  return r.v;
}

// async global->LDS, 16B per lane; LDS dest is wave-uniform base + lane*16
__device__ __forceinline__ void gload16(const u16* g, u16* l) {
  __builtin_amdgcn_global_load_lds(
      (__attribute__((address_space(1))) u32*)(u16*)g,
      (__attribute__((address_space(3))) u32*)l, 16, 0, 0);
}

// ---------------- fp32 -> bf16 bulk convert (8 elems/thread) -----------------
__global__ __launch_bounds__(256) void cvt_k(
    const float* __restrict__ in, u16* __restrict__ out) {
  const long i = ((long)blockIdx.x * 256 + threadIdx.x) * 8;
  *(uint4*)&out[i] = load8(&in[i]);
}

// ---------- 64x64 tile transpose + fp32->bf16: dst[c][r] = src[r][c] ---------
__global__ __launch_bounds__(256) void transpose_k(
    const float* __restrict__ src, u16* __restrict__ dst, int srcLd, int dstLd) {
  __shared__ u16 t[64][72];
  const int r0 = blockIdx.y * 64, c0 = blockIdx.x * 64;
  const int tid = threadIdx.x;
  for (int p = 0; p < 16; ++p) {
    int idx = p * 256 + tid, r = idx >> 6, c = idx & 63;
    t[r][c] = f2bf(src[(long)(r0 + r) * srcLd + (c0 + c)]);
  }
  __syncthreads();
  for (int p = 0; p < 16; ++p) {
    int idx = p * 256 + tid, r = idx >> 6, c = idx & 63;
    dst[(long)(c0 + r) * dstLd + (r0 + c)] = t[c][r];
  }
}

// -------- GEMM (all-bf16): C = A[MxK] * Bt[NxK]^T, m97-style staging --------
// 128x128 tile, BK=32, 4 waves (2x2), global_load_lds width-16, linear LDS.
// grid must be dim3(8, M/128): N=1024 fixed. XCD-bijective swizzle (nwg%8==0).
// MODE 1: f32 out at row*ldc + col
// MODE 2: bf16 out scattered to [b,h,s,d] from row=(b,s), col=(h,d)
// MODE 3: bf16 out scattered to [b,h,d,s] from row=(b,s), col=(h,d)
// MODE 4: bf16 out at row*ldc + col
template<int MODE>
__global__ __launch_bounds__(256) void gemm16(
    const u16* __restrict__ A, const u16* __restrict__ Bt, void* __restrict__ C,
    int K, int lda, int ldb, int ldc) {
  __shared__ __align__(16) u16 As[128 * 32];   // linear [row][32]
  __shared__ __align__(16) u16 Bs[128 * 32];
  const int tid = threadIdx.x;
  const int wave = tid >> 6, lane = tid & 63;
  const int quad = lane >> 4, l16 = lane & 15;
  const int wm = wave >> 1, wn = wave & 1;
  // XCD swizzle: XCD x gets a contiguous chunk of 64 tiles (8 A-panels reused)
  const int bid = blockIdx.y * 8 + blockIdx.x;
  const int cpx = (gridDim.y * 8) >> 3;
  const int swz = (bid & 7) * cpx + (bid >> 3);
  const int m0 = (swz >> 3) * 128, n0 = (swz & 7) * 128;

  f32x4 acc[4][4];
#pragma unroll
  for (int i = 0; i < 4; ++i)
#pragma unroll
    for (int j = 0; j < 4; ++j) acc[i][j] = (f32x4){0.f, 0.f, 0.f, 0.f};

  // staging: wave w owns rows [32w, 32w+32). lane l -> row l>>2, 16B seg l&3.
  const int srow = lane >> 2, scol = (lane & 3) * 8;
  const u16* ga = &A[(long)(m0 + wave * 32 + srow) * lda + scol];
  const u16* gb = &Bt[(long)(n0 + wave * 32 + srow) * ldb + scol];
  u16* la0 = &As[(wave * 32) * 32];
  u16* la1 = &As[(wave * 32 + 16) * 32];
  u16* lb0 = &Bs[(wave * 32) * 32];
  u16* lb1 = &Bs[(wave * 32 + 16) * 32];

  for (int k0 = 0; k0 < K; k0 += 32) {
    __syncthreads();
    gload16(ga + k0,            la0);
    gload16(ga + k0 + 16 * lda, la1);
    gload16(gb + k0,            lb0);
    gload16(gb + k0 + 16 * ldb, lb1);
    __syncthreads();   // drains vmcnt (compiler inserts waitcnt before barrier)
    bf16x8 af[4], bfr[4];
#pragma unroll
    for (int i = 0; i < 4; ++i)
      af[i] = *(const bf16x8*)&As[(wm * 64 + i * 16 + l16) * 32 + quad * 8];
#pragma unroll
    for (int j = 0; j < 4; ++j)
      bfr[j] = *(const bf16x8*)&Bs[(wn * 64 + j * 16 + l16) * 32 + quad * 8];
#pragma unroll
    for (int i = 0; i < 4; ++i)
#pragma unroll
      for (int j = 0; j < 4; ++j)
        acc[i][j] = __builtin_amdgcn_mfma_f32_16x16x32_bf16(af[i], bfr[j], acc[i][j], 0, 0, 0);
  }

#pragma unroll
  for (int i = 0; i < 4; ++i) {
    const int rowb = m0 + wm * 64 + i * 16 + quad * 4;
#pragma unroll
    for (int j = 0; j < 4; ++j) {
      const int col = n0 + wn * 64 + j * 16 + l16;
#pragma unroll
      for (int r = 0; r < 4; ++r) {
        const float v = acc[i][j][r];
        const int row = rowb + r;
        if (MODE == 1) {
          ((float*)C)[(long)row * ldc + col] = v;
        } else if (MODE == 2) {
          int bb = row >> 10, ss = row & 1023, hh = col >> 6, dd = col & 63;
          ((u16*)C)[((long)(bb * NHEAD + hh) * SEQ + ss) * DHEAD + dd] = f2bf(v);
        } else if (MODE == 3) {
          int bb = row >> 10, ss = row & 1023, hh = col >> 6, dd = col & 63;
          ((u16*)C)[((long)(bb * NHEAD + hh) * DHEAD + dd) * SEQ + ss] = f2bf(v);
        } else {
          ((u16*)C)[(long)row * ldc + col] = f2bf(v);
        }
      }
    }
  }
}

// ---- fused attention: scores + softmax -> P (fp32, coalesced) + P@V -> Ctx --
// grid: x = q-tile (S/64), y = head, z = batch. 4 waves, each owns 16 q rows.
// T14 async-stage: K/V/mask for tile st+1 are issued (to registers) right
// after tile st's LDS is populated, hiding HBM/L2 latency under compute.
// Ps transpose handoff is intra-wave (each wave owns rows [16w,16w+16)) ->
// no barrier needed between Ps write and PV read / P store.
__global__ __launch_bounds__(256, 4) void attn_kernel(
    const u16* __restrict__ Qb, const u16* __restrict__ Kb,
    const u16* __restrict__ Vt, const float* __restrict__ Msk,
    float* __restrict__ P, u16* __restrict__ Ctx) {
  __shared__ __align__(16) u16 QVs[64][72];   // Q tile; reused as V tile in pass 1
  __shared__ __align__(16) u16 Ks[64][72];
  __shared__ __align__(16) float Ps[64][68];  // fp32 P tile (transpose staging)
  const int tid = threadIdx.x, wave = tid >> 6, lane = tid & 63;
  const int quad = lane >> 4, l16 = lane & 15;
  const int q0 = blockIdx.x * 64, h = blockIdx.y, b = blockIdx.z;
  const long bh = (long)b * NHEAD + h;
  const u16* Qp = Qb + ((long)b * SEQ + q0) * FDIM + h * DHEAD;
  const u16* Kp = Kb + bh * SEQ * DHEAD;
  const u16* Vp = Vt + bh * (long)DHEAD * SEQ;
  const float* Mp = Msk + ((long)b * SEQ + q0) * SEQ;
  float* Pp = P + bh * (long)SEQ * SEQ + (long)q0 * SEQ;
  u16* Cp = Ctx + ((long)b * SEQ + q0) * FDIM + h * DHEAD;

  const int lr = tid >> 3, lc = (tid & 7) * 8;  // staging coords
  const int qrb = wave * 16 + quad * 4;         // base q-row of this lane

  {
    *(uint4*)&QVs[lr][lc]      = *(const uint4*)&Qp[(long)lr * FDIM + lc];
    *(uint4*)&QVs[lr + 32][lc] = *(const uint4*)&Qp[(long)(lr + 32) * FDIM + lc];
  }
  __syncthreads();
  const bf16x8 aq0 = *(const bf16x8*)&QVs[wave * 16 + l16][quad * 8];
  const bf16x8 aq1 = *(const bf16x8*)&QVs[wave * 16 + l16][32 + quad * 8];

  float m[4], l[4], rl[4];
#pragma unroll
  for (int r = 0; r < 4; ++r) { m[r] = -3.0e38f; l[r] = 0.f; }

  // ---- pass 0 prologue: prefetch K + mask for tile 0 ----
  uint4 kr0 = *(const uint4*)&Kp[lr * DHEAD + lc];
  uint4 kr1 = *(const uint4*)&Kp[(lr + 32) * DHEAD + lc];
  float mc[4][4];
#pragma unroll
  for (int j = 0; j < 4; ++j)
#pragma unroll
    for (int r = 0; r < 4; ++r)
      mc[j][r] = Mp[(long)(qrb + r) * SEQ + j * 16 + l16];

  // ---- pass 0: running row max + exp-sum ----
  for (int st = 0; st < SEQ / 64; ++st) {
    __syncthreads();                     // previous tile's LDS reads done
    *(uint4*)&Ks[lr][lc]      = kr0;
    *(uint4*)&Ks[lr + 32][lc] = kr1;
    __syncthreads();                     // tile st ready
    const int skn = ((st + 1) & 15) * 64;   // st=15 reloads tile 0 (harmless)
    kr0 = *(const uint4*)&Kp[(skn + lr) * DHEAD + lc];
    kr1 = *(const uint4*)&Kp[(skn + lr + 32) * DHEAD + lc];
    float mn_[4][4];
#pragma unroll
    for (int j = 0; j < 4; ++j)
#pragma unroll
      for (int r = 0; r < 4; ++r)
        mn_[j][r] = Mp[(long)(qrb + r) * SEQ + skn + j * 16 + l16];

    float sv[4][4];
#pragma unroll
    for (int j = 0; j < 4; ++j) {
      bf16x8 bk0 = *(const bf16x8*)&Ks[j * 16 + l16][quad * 8];
      bf16x8 bk1 = *(const bf16x8*)&Ks[j * 16 + l16][32 + quad * 8];
      f32x4 sc = (f32x4){0.f, 0.f, 0.f, 0.f};
      __builtin_amdgcn_s_setprio(1);
      sc = __builtin_amdgcn_mfma_f32_16x16x32_bf16(aq0, bk0, sc, 0, 0, 0);
      sc = __builtin_amdgcn_mfma_f32_16x16x32_bf16(aq1, bk1, sc, 0, 0, 0);
      __builtin_amdgcn_s_setprio(0);
#pragma unroll
      for (int r = 0; r < 4; ++r)
        sv[j][r] = sc[r] * 0.125f + (mc[j][r] - 1.0f) * 1.0e9f;
    }
#pragma unroll
    for (int r = 0; r < 4; ++r) {
      float tm = fmaxf(fmaxf(sv[0][r], sv[1][r]), fmaxf(sv[2][r], sv[3][r]));
#pragma unroll
      for (int off = 1; off < 16; off <<= 1) tm = fmaxf(tm, __shfl_xor(tm, off, 64));
      float mn = fmaxf(m[r], tm);
      float ps = __expf(sv[0][r] - mn) + __expf(sv[1][r] - mn) +
                 __expf(sv[2][r] - mn) + __expf(sv[3][r] - mn);
#pragma unroll
      for (int off = 1; off < 16; off <<= 1) ps += __shfl_xor(ps, off, 64);
      l[r] = l[r] * __expf(m[r] - mn) + ps;
      m[r] = mn;
    }
#pragma unroll
    for (int j = 0; j < 4; ++j)
#pragma unroll
      for (int r = 0; r < 4; ++r) mc[j][r] = mn_[j][r];
  }

  // ---- pass 1 prologue: issue K/V/mask tile-0 loads, then compute rl ----
  kr0 = *(const uint4*)&Kp[lr * DHEAD + lc];
  kr1 = *(const uint4*)&Kp[(lr + 32) * DHEAD + lc];
  uint4 vr0 = *(const uint4*)&Vp[(long)lr * SEQ + lc];
  uint4 vr1 = *(const uint4*)&Vp[(long)(lr + 32) * SEQ + lc];
#pragma unroll
  for (int j = 0; j < 4; ++j)
#pragma unroll
    for (int r = 0; r < 4; ++r)
      mc[j][r] = Mp[(long)(qrb + r) * SEQ + j * 16 + l16];
#pragma unroll
  for (int r = 0; r < 4; ++r) rl[r] = 1.0f / l[r];

  // ---- pass 1: normalized P tile -> LDS -> {P store (coalesced), PV MFMA} ----
  f32x4 acc[4];
#pragma unroll
  for (int n = 0; n < 4; ++n) acc[n] = (f32x4){0.f, 0.f, 0.f, 0.f};

  for (int st = 0; st < SEQ / 64; ++st) {
    const int sk0 = st * 64;
    __syncthreads();                     // previous tile's LDS reads done
    *(uint4*)&Ks[lr][lc]       = kr0;
    *(uint4*)&Ks[lr + 32][lc]  = kr1;
    *(uint4*)&QVs[lr][lc]      = vr0;
    *(uint4*)&QVs[lr + 32][lc] = vr1;
    __syncthreads();                     // tile st ready
    const int skn = ((st + 1) & 15) * 64;
    kr0 = *(const uint4*)&Kp[(skn + lr) * DHEAD + lc];
    kr1 = *(const uint4*)&Kp[(skn + lr + 32) * DHEAD + lc];
    vr0 = *(const uint4*)&Vp[(long)lr * SEQ + skn + lc];
    vr1 = *(const uint4*)&Vp[(long)(lr + 32) * SEQ + skn + lc];
    float mn_[4][4];
#pragma unroll
    for (int j = 0; j < 4; ++j)
#pragma unroll
      for (int r = 0; r < 4; ++r)
        mn_[j][r] = Mp[(long)(qrb + r) * SEQ + skn + j * 16 + l16];

#pragma unroll
    for (int j = 0; j < 4; ++j) {
      bf16x8 bk0 = *(const bf16x8*)&Ks[j * 16 + l16][quad * 8];
      bf16x8 bk1 = *(const bf16x8*)&Ks[j * 16 + l16][32 + quad * 8];
      f32x4 sc = (f32x4){0.f, 0.f, 0.f, 0.f};
      __builtin_amdgcn_s_setprio(1);
      sc = __builtin_amdgcn_mfma_f32_16x16x32_bf16(aq0, bk0, sc, 0, 0, 0);
      sc = __builtin_amdgcn_mfma_f32_16x16x32_bf16(aq1, bk1, sc, 0, 0, 0);
      __builtin_amdgcn_s_setprio(0);
#pragma unroll
      for (int r = 0; r < 4; ++r) {
        float s = sc[r] * 0.125f + (mc[j][r] - 1.0f) * 1.0e9f;
        Ps[qrb + r][j * 16 + l16] = __expf(s - m[r]) * rl[r];
      }
    }
    // NO barrier: Ps rows [16w,16w+16) are produced and consumed by wave w only
    // PV: acc[n] += P_tile(wave's 16 rows) x V_tile
#pragma unroll
    for (int ks = 0; ks < 2; ++ks) {
      const float* pr = &Ps[wave * 16 + l16][ks * 32 + quad * 8];
      f32x4 plo = *(const f32x4*)pr;
      f32x4 phi = *(const f32x4*)(pr + 4);
      union { u16 h[8]; bf16x8 v; } pa;
      pa.h[0] = f2bf(plo.x); pa.h[1] = f2bf(plo.y);
      pa.h[2] = f2bf(plo.z); pa.h[3] = f2bf(plo.w);
      pa.h[4] = f2bf(phi.x); pa.h[5] = f2bf(phi.y);
      pa.h[6] = f2bf(phi.z); pa.h[7] = f2bf(phi.w);
      __builtin_amdgcn_s_setprio(1);
#pragma unroll
      for (int n = 0; n < 4; ++n) {
        bf16x8 bv = *(const bf16x8*)&QVs[n * 16 + l16][ks * 32 + quad * 8];
        acc[n] = __builtin_amdgcn_mfma_f32_16x16x32_bf16(pa.v, bv, acc[n], 0, 0, 0);
      }
      __builtin_amdgcn_s_setprio(0);
    }
    // coalesced nontemporal global P write: 4 rows x 256B per instruction
#pragma unroll
    for (int rr = 0; rr < 4; ++rr) {
      const int row = wave * 16 + rr * 4 + quad;
      f32x4 val = *(const f32x4*)&Ps[row][l16 * 4];
      __builtin_nontemporal_store(val, (f32x4*)&Pp[(long)row * SEQ + sk0 + l16 * 4]);
    }
#pragma unroll
    for (int j = 0; j < 4; ++j)
#pragma unroll
      for (int r = 0; r < 4; ++r) mc[j][r] = mn_[j][r];
  }

  // ---- ctx epilogue -> Ctx bf16 [b,s,(h,d)] (in-place over Q tile) ----
#pragma unroll
  for (int n = 0; n < 4; ++n)
#pragma unroll
    for (int r = 0; r < 4; ++r)
      Cp[(long)(qrb + r) * FDIM + n * 16 + l16] = f2bf(acc[n][r]);
}

// --------------- residual + LayerNorm (weight=1, bias=0) ---------------------
__global__ __launch_bounds__(256) void ln_kernel(
    const float* __restrict__ O, const float* __restrict__ Xq, float* __restrict__ out) {
  const int row = blockIdx.x, tid = threadIdx.x;
  const float4 o = *(const float4*)&O[(long)row * FDIM + tid * 4];
  const float4 q = *(const float4*)&Xq[(long)row * FDIM + tid * 4];
  float x[4] = { o.x + q.x, o.y + q.y, o.z + q.z, o.w + q.w };
  float s  = x[0] + x[1] + x[2] + x[3];
  float s2 = x[0]*x[0] + x[1]*x[1] + x[2]*x[2] + x[3]*x[3];
#pragma unroll
  for (int off = 32; off; off >>= 1) {
    s  += __shfl_xor(s, off, 64);
    s2 += __shfl_xor(s2, off, 64);
  }
  __shared__ float red[8];
  const int wave = tid >> 6, lane = tid & 63;
  if (lane == 0) { red[wave] = s; red[4 + wave] = s2; }
  __syncthreads();
  s  = red[0] + red[1] + red[2] + red[3];
  s2 = red[4] + red[5] + red[6] + red[7];
  const float mu = s * (1.0f / FDIM);
  const float var = s2 * (1.0f / FDIM) - mu * mu;
  const float rs = rsqrtf(var + 1e-5f);
  float4 res;
  res.x = (x[0] - mu) * rs; res.y = (x[1] - mu) * rs;
  res.z = (x[2] - mu) * rs; res.w = (x[3] - mu) * rs;
  *(float4*)&out[(long)row * FDIM + tid * 4] = res;
}

extern "C" void kernel_launch(void* const* d_in, const int* in_sizes, int n_in,
                              void* d_out, int out_size, void* d_ws, size_t ws_size,
                              hipStream_t stream) {
  const float* Xq = (const float*)d_in[0];
  const float* Xk = (const float*)d_in[1];
  const float* Xv = (const float*)d_in[2];
  const float* Mk = (const float*)d_in[3];
  const float* Wq = (const float*)d_in[4];
  const float* Wk = (const float*)d_in[5];
  const float* Wv = (const float*)d_in[6];
  const float* Wo = (const float*)d_in[7];

  // ws layout (u16 units), total 56 MB:
  //  [0,1M)=WtQ [1M,2M)=WtK [2M,3M)=WtV [3M,4M)=WtO
  //  [4M,12M)=Qb [b,s,(h,d)] bf16 -> overwritten in place with Ctx by attn
  //  [12M,20M)=Kb [b,h,s,d]   [20M,28M)=Vt [b,h,d,s]
  //  alias: O(f32,32MB) <- Kb+Vt region after attn (both dead)
  u16* ws  = (u16*)d_ws;
  const size_t M = 1u << 20;
  u16* WtQ = ws;
  u16* WtK = ws + 1 * M;
  u16* WtV = ws + 2 * M;
  u16* WtO = ws + 3 * M;
  u16* Qb  = ws + 4 * M;             // [b,s,(h,d)] bf16; becomes Ctx
  u16* Kb  = ws + 12 * M;            // [b,h,s,d] bf16
  u16* Vt  = ws + 20 * M;            // [b,h,d,s] bf16
  float* O = (float*)(ws + 12 * M);  // fp32 (Kb,Vt dead after attn)

  float* out = (float*)d_out;                            // [b,s,f] fp32
  float* P   = out + (size_t)BATCH * SEQ * FDIM;         // attn probs fp32

  // bf16 input copies live in the (currently dead) P region of d_out:
  // attn overwrites them only after the projections have consumed them.
  u16* Xqb = (u16*)P;
  u16* Xkb = (u16*)P + 8 * M;
  u16* Xvb = (u16*)P + 16 * M;

  // fp32 -> bf16 bulk converts (8M elems each)
  cvt_k<<<dim3(4096, 1, 1), 256, 0, stream>>>(Xq, Xqb);
  cvt_k<<<dim3(4096, 1, 1), 256, 0, stream>>>(Xk, Xkb);
  cvt_k<<<dim3(4096, 1, 1), 256, 0, stream>>>(Xv, Xvb);
  // weight transposes + bf16 convert: Wt[n][k] = W[k][n]
  transpose_k<<<dim3(16, 16, 1), 256, 0, stream>>>(Wq, WtQ, FDIM, FDIM);
  transpose_k<<<dim3(16, 16, 1), 256, 0, stream>>>(Wk, WtK, FDIM, FDIM);
  transpose_k<<<dim3(16, 16, 1), 256, 0, stream>>>(Wv, WtV, FDIM, FDIM);
  transpose_k<<<dim3(16, 16, 1), 256, 0, stream>>>(Wo, WtO, FDIM, FDIM);
  // projections (all-bf16, global_load_lds staging)
  gemm16<4><<<dim3(8, 64, 1), 256, 0, stream>>>(Xqb, WtQ, Qb, FDIM, FDIM, FDIM, FDIM);
  gemm16<2><<<dim3(8, 64, 1), 256, 0, stream>>>(Xkb, WtK, Kb, FDIM, FDIM, FDIM, 0);
  gemm16<3><<<dim3(8, 64, 1), 256, 0, stream>>>(Xvb, WtV, Vt, FDIM, FDIM, FDIM, 0);
  // fused scores + softmax -> P, and P@V -> Ctx (in place over Qb)
  attn_kernel<<<dim3(SEQ / 64, NHEAD, BATCH), 256, 0, stream>>>(Qb, Kb, Vt, Mk, P, Qb);
  // out projection -> O (fp32)
  gemm16<1><<<dim3(8, 64, 1), 256, 0, stream>>>(Qb, WtO, O, FDIM, FDIM, FDIM, FDIM);
  // residual + LayerNorm -> out (fp32)
  ln_kernel<<<dim3(BATCH * SEQ, 1, 1), 256, 0, stream>>>(O, Xq, out);
}